// Round 8
// baseline (74.449 us; speedup 1.0000x reference)
//
#include <hip/hip_runtime.h>

// CapsNet conv + dynamic routing, single fused kernel (MI355X / gfx950).
// One block (1024 thr = 16 waves) per pixel; votes^T in the MFMA accumulator.
// R8: (a) remaining xor16/xor32 shuffles moved from LDS pipe to VALU via
// v_permlane{16,32}_swap_b32 (swap(x,x) -> two results whose sum is the
// butterfly sum); (b) redundant per-lane squash removes the act array, its
// barrier and round-trip (7 -> 5 barriers); (c) outputs stored straight from
// writer-lane registers.
//
// Lane decomposition (l = lane, q = l>>4, il = l&15), wave (wf, wi):
//   acc[tf][ti].r = votes[ i = 64*wi+16*ti+il ][ f = 64*wf+16*tf+4*q+r ]
//   c = 8*wf + 2*tf + (q>>1)   (capsule),  n = 4*(q&1) + r

#define BS 16
#define CI 256
#define CO 32
#define NO 8
#define HI 20
#define WI 20
#define HO 6
#define WO 6
#define NPIX 36
#define NTAP 81
#define XP 104          // k pitch (bf16), 2-way banks (free)
#define NBLK 576

typedef __attribute__((ext_vector_type(8))) short bf16x8;
typedef __attribute__((ext_vector_type(4))) float f32x4;

__device__ __forceinline__ ushort f2bf(float x) {
    union { float f; unsigned u; } v; v.f = x;
    unsigned r = v.u + 0x7FFFu + ((v.u >> 16) & 1u);   // RNE
    return (ushort)(r >> 16);
}

// ---- VALU cross-lane reductions ----
// DPP (within 16-lane rows)
template<int CTRL>
__device__ __forceinline__ float dpp_radd(float v) {
    int s = __builtin_amdgcn_update_dpp(0, __float_as_int(v), CTRL, 0xF, 0xF, true);
    return v + __int_as_float(s);
}
__device__ __forceinline__ float row16_sum_tail(float v) {
    v = dpp_radd<0x111>(v);   // row_shr:1
    v = dpp_radd<0x112>(v);   // row_shr:2
    v = dpp_radd<0x114>(v);   // row_shr:4
    v = dpp_radd<0x118>(v);   // row_shr:8
    return v;                 // lane 15 of each row holds the row sum
}
// xor-16 / xor-32 butterfly sums on the VALU pipe (gfx950 permlane*_swap):
// swap(x,x) returns {a,b} with a+b == x + x[lane^K] in every lane.
#if __has_builtin(__builtin_amdgcn_permlane16_swap)
typedef unsigned u32x2 __attribute__((ext_vector_type(2)));
__device__ __forceinline__ float xor16_sum(float v) {
    u32x2 r = __builtin_amdgcn_permlane16_swap(__float_as_uint(v), __float_as_uint(v), false, false);
    return __uint_as_float(r.x) + __uint_as_float(r.y);
}
#else
__device__ __forceinline__ float xor16_sum(float v) { return v + __shfl_xor(v, 16, 64); }
#endif
#if __has_builtin(__builtin_amdgcn_permlane32_swap)
typedef unsigned u32x2b __attribute__((ext_vector_type(2)));
__device__ __forceinline__ float xor32_sum(float v) {
    u32x2b r = __builtin_amdgcn_permlane32_swap(__float_as_uint(v), __float_as_uint(v), false, false);
    return __uint_as_float(r.x) + __uint_as_float(r.y);
}
#else
__device__ __forceinline__ float xor32_sum(float v) { return v + __shfl_xor(v, 32, 64); }
#endif

__global__ __launch_bounds__(1024) void caps_kernel(
    const float* __restrict__ x,     // [16,256,1,20,20]
    const float* __restrict__ Wt,    // [256,1,9,9]
    const float* __restrict__ bias,  // [32,8,1,1]
    float* __restrict__ out)         // [16,32,8,6,6]
{
    __shared__ __align__(16) ushort xw[CI * XP];        // 53248 B
    __shared__ __align__(16) ushort wl[CO * NO * XP];   // 53248 B
    __shared__ __align__(16) float  smx[4 * 256];       // softmax partials [wf][i]
    __shared__ __align__(16) float  pre[4 * 256];       // preact partials [wi][c*8+n]
    __shared__ __align__(16) float  bb[256];            // bias staged

    const int t   = threadIdx.x, blk = blockIdx.x;
    const int b   = blk & 15;          // XCD-local image mapping
    const int hw  = blk >> 4;          // 0..35
    const int h   = hw / WO, w = hw % WO;
    const int w2  = 2 * w;

    const int wid = t >> 6, l = t & 63;
    const int q = l >> 4, il = l & 15;
    const int wf = wid >> 2, wi = wid & 3;

    // ---- stage W (k-major, pitch 104) + bias
    for (int p = t; p < CO * NO * NTAP; p += 1024) {
        int f = p / NTAP, k = p - f * NTAP;
        wl[f * XP + k] = f2bf(Wt[p]);
    }
    if (t < 256) bb[t] = bias[t];
    // ---- zero pads k in [81,104) for both tiles
    {
        int i = t >> 2, s4 = t & 3;
        #pragma unroll
        for (int j = 0; j < 6; ++j) {
            int k = NTAP + s4 * 6 + j;
            if (k < XP) { xw[i * XP + k] = 0; wl[i * XP + k] = 0; }
        }
    }
    // ---- stage x window, coalesced float4 quads
    #pragma unroll
    for (int pass = 0; pass < 9; ++pass) {
        int idx = pass * 1024 + t;
        int q4 = idx & 3, r = idx >> 2;
        int kh = r % 9, i = r / 9;
        float4 v = *(const float4*)(x + ((b * CI + i) * HI + (2 * h + kh)) * WI + 4 * q4);
        const float* ve = &v.x;
        #pragma unroll
        for (int e = 0; e < 4; ++e) {
            int kw = 4 * q4 + e - w2;
            if ((unsigned)kw < 9u) xw[i * XP + kh * 9 + kw] = f2bf(ve[e]);
        }
    }
    if (w >= 4) {
        for (int r = t; r < CI * 9; r += 1024) {
            int kh = r % 9, i = r / 9;
            float4 v = *(const float4*)(x + ((b * CI + i) * HI + (2 * h + kh)) * WI + 16);
            const float* ve = &v.x;
            #pragma unroll
            for (int e = 0; e < 4; ++e) {
                int kw = 16 + e - w2;
                if ((unsigned)kw < 9u) xw[i * XP + kh * 9 + kw] = f2bf(ve[e]);
            }
        }
    }

    __syncthreads();

    // ---- conv via MFMA: votes^T
    f32x4 acc[4][4];
    #pragma unroll
    for (int tf = 0; tf < 4; ++tf)
        #pragma unroll
        for (int ti = 0; ti < 4; ++ti)
            acc[tf][ti] = (f32x4){0.f, 0.f, 0.f, 0.f};

    #pragma unroll
    for (int ks = 0; ks < 3; ++ks) {
        const int ko = ks * 32 + q * 8;
        bf16x8 af[4], bv[4];
        #pragma unroll
        for (int tf = 0; tf < 4; ++tf)
            af[tf] = *(const bf16x8*)&wl[(wf * 64 + tf * 16 + il) * XP + ko];
        #pragma unroll
        for (int ti = 0; ti < 4; ++ti)
            bv[ti] = *(const bf16x8*)&xw[(wi * 64 + ti * 16 + il) * XP + ko];
        #pragma unroll
        for (int tf = 0; tf < 4; ++tf)
            #pragma unroll
            for (int ti = 0; ti < 4; ++ti)
                acc[tf][ti] = __builtin_amdgcn_mfma_f32_16x16x32_bf16(
                    af[tf], bv[ti], acc[tf][ti], 0, 0, 0);
    }
    // No barrier: routing uses separate LDS buffers (smx/pre).

    // ---- dynamic routing, 3 iterations
    float lg[4][4];
    #pragma unroll
    for (int tf = 0; tf < 4; ++tf)
        #pragma unroll
        for (int ti = 0; ti < 4; ++ti) lg[tf][ti] = 0.f;

    #pragma unroll
    for (int it = 0; it < 3; ++it) {
        // --- preact partials pp[tf][r]
        float pp[4][4];
        if (it == 0) {
            #pragma unroll
            for (int tf = 0; tf < 4; ++tf)
                #pragma unroll
                for (int r = 0; r < 4; ++r)
                    pp[tf][r] = (acc[tf][0][r] + acc[tf][1][r]
                               + acc[tf][2][r] + acc[tf][3][r]) * 0.03125f;
        } else {
            float e[4][4], srow[4] = {0.f, 0.f, 0.f, 0.f};
            #pragma unroll
            for (int tf = 0; tf < 4; ++tf)
                #pragma unroll
                for (int ti = 0; ti < 4; ++ti) {
                    e[tf][ti] = __expf(lg[tf][ti]);
                    srow[ti] += e[tf][ti];
                }
            #pragma unroll
            for (int ti = 0; ti < 4; ++ti)
                srow[ti] = xor32_sum(srow[ti]);    // other c-half (q>>1), VALU
            if (q == 0) {
                #pragma unroll
                for (int ti = 0; ti < 4; ++ti)
                    smx[wf * 256 + wi * 64 + ti * 16 + il] = srow[ti];
            }
            __syncthreads();
            float rtot[4];
            #pragma unroll
            for (int ti = 0; ti < 4; ++ti) {
                int i = wi * 64 + ti * 16 + il;
                rtot[ti] = __builtin_amdgcn_rcpf(
                    smx[i] + smx[256 + i] + smx[512 + i] + smx[768 + i]);
            }
            float route[4][4];
            #pragma unroll
            for (int tf = 0; tf < 4; ++tf)
                #pragma unroll
                for (int ti = 0; ti < 4; ++ti) route[tf][ti] = e[tf][ti] * rtot[ti];
            #pragma unroll
            for (int tf = 0; tf < 4; ++tf)
                #pragma unroll
                for (int r = 0; r < 4; ++r)
                    pp[tf][r] = route[tf][0] * acc[tf][0][r] + route[tf][1] * acc[tf][1][r]
                              + route[tf][2] * acc[tf][2][r] + route[tf][3] * acc[tf][3][r];
        }

        // --- reduce over il (16 i-lanes) on the VALU pipe (DPP)
        #pragma unroll
        for (int tf = 0; tf < 4; ++tf)
            #pragma unroll
            for (int r = 0; r < 4; ++r)
                pp[tf][r] = row16_sum_tail(pp[tf][r]);
        if (il == 15) {
            #pragma unroll
            for (int tf = 0; tf < 4; ++tf) {
                int c = wf * 8 + tf * 2 + (q >> 1);
                f32x4 vv = {pp[tf][0], pp[tf][1], pp[tf][2], pp[tf][3]};
                *(f32x4*)&pre[wi * 256 + c * 8 + (q & 1) * 4] = vv;
            }
        }
        __syncthreads();
        // NOTE: next iteration's pre-writes are separated from this
        // iteration's pre-reads (below) by the next iteration's smx barrier.

        // --- redundant per-lane squash + distances / output, per tf
        #pragma unroll
        for (int tf = 0; tf < 4; ++tf) {
            const int c8 = (wf * 8 + tf * 2 + (q >> 1)) * 8 + (q & 1) * 4;
            f32x4 p0 = *(const f32x4*)&pre[c8];
            f32x4 p1 = *(const f32x4*)&pre[256 + c8];
            f32x4 p2 = *(const f32x4*)&pre[512 + c8];
            f32x4 p3 = *(const f32x4*)&pre[768 + c8];
            f32x4 bv4 = *(const f32x4*)&bb[c8];
            float s[4], sq4 = 0.f;
            #pragma unroll
            for (int r = 0; r < 4; ++r) {
                s[r] = bv4[r] + p0[r] + p1[r] + p2[r] + p3[r];
                sq4 += s[r] * s[r];
            }
            float sq = xor16_sum(sq4);           // other n-half, VALU
            float scale = __builtin_amdgcn_sqrtf(sq) * __builtin_amdgcn_rcpf(1.f + sq);
            if (it < 2) {
                #pragma unroll
                for (int ti = 0; ti < 4; ++ti) {
                    float d = acc[tf][ti][0] * (s[0] * scale)
                            + acc[tf][ti][1] * (s[1] * scale)
                            + acc[tf][ti][2] * (s[2] * scale)
                            + acc[tf][ti][3] * (s[3] * scale);
                    lg[tf][ti] += xor16_sum(d);  // add other n-half, VALU
                }
            } else if (wi == 0 && il == 0) {
                const int c = wf * 8 + tf * 2 + (q >> 1);
                #pragma unroll
                for (int r = 0; r < 4; ++r)
                    out[((b * CO + c) * NO + (4 * (q & 1) + r)) * NPIX + hw] = s[r] * scale;
            }
        }
    }
}

extern "C" void kernel_launch(void* const* d_in, const int* in_sizes, int n_in,
                              void* d_out, int out_size, void* d_ws, size_t ws_size,
                              hipStream_t stream) {
    const float* x    = (const float*)d_in[0];
    const float* Wt   = (const float*)d_in[1];
    const float* bias = (const float*)d_in[2];
    float* out = (float*)d_out;
    caps_kernel<<<NBLK, 1024, 0, stream>>>(x, Wt, bias, out);
}

// Round 9
// 57.197 us; speedup vs baseline: 1.3016x; 1.3016x over previous
//
#include <hip/hip_runtime.h>

// CapsNet conv + dynamic routing, single fused kernel (MI355X / gfx950).
// R9 = R7 (verified 48.3 us) + (a) persistent blocks: grid=256, each block
// owns 2-3 pixels (pid = blk + 256*p, same image), W/bias/pads staged once,
// next pixel's x staged between conv and routing to fill routing stalls;
// (b) remaining xor16/xor32 shuffles moved to VALU via permlane*_swap
// (validated in R8; R8's regression was a spill from the redundant-squash
// rewrite, which is NOT carried here).
//
// Lane decomposition (l = lane, q = l>>4, il = l&15), wave (wf, wi):
//   acc[tf][ti].r = votes[ i = 64*wi+16*ti+il ][ f = 64*wf+16*tf+4*q+r ]
//   c = 8*wf + 2*tf + (q>>1)   (capsule),  n = 4*(q&1) + r

#define BS 16
#define CI 256
#define CO 32
#define NO 8
#define HI 20
#define WI 20
#define HO 6
#define WO 6
#define NPIX 36
#define NTAP 81
#define XP 104          // k pitch (bf16), 2-way banks (free)
#define NBLK 256

typedef __attribute__((ext_vector_type(8))) short bf16x8;
typedef __attribute__((ext_vector_type(4))) float f32x4;

__device__ __forceinline__ ushort f2bf(float x) {
    union { float f; unsigned u; } v; v.f = x;
    unsigned r = v.u + 0x7FFFu + ((v.u >> 16) & 1u);   // RNE
    return (ushort)(r >> 16);
}

// ---- VALU cross-lane reductions ----
template<int CTRL>
__device__ __forceinline__ float dpp_radd(float v) {
    int s = __builtin_amdgcn_update_dpp(0, __float_as_int(v), CTRL, 0xF, 0xF, true);
    return v + __int_as_float(s);
}
__device__ __forceinline__ float row16_sum_tail(float v) {
    v = dpp_radd<0x111>(v);   // row_shr:1
    v = dpp_radd<0x112>(v);   // row_shr:2
    v = dpp_radd<0x114>(v);   // row_shr:4
    v = dpp_radd<0x118>(v);   // row_shr:8
    return v;                 // lane 15 of each row holds the row sum
}
__device__ __forceinline__ float grp8_sum_all(float v) {
    v = dpp_radd<0xB1>(v);    // quad_perm [1,0,3,2]  (xor 1)
    v = dpp_radd<0x4E>(v);    // quad_perm [2,3,0,1]  (xor 2)
    v = dpp_radd<0x141>(v);   // row_half_mirror      (other quad)
    return v;
}
#if __has_builtin(__builtin_amdgcn_permlane16_swap)
typedef unsigned u32x2 __attribute__((ext_vector_type(2)));
__device__ __forceinline__ float xor16_sum(float v) {
    u32x2 r = __builtin_amdgcn_permlane16_swap(__float_as_uint(v), __float_as_uint(v), false, false);
    return __uint_as_float(r.x) + __uint_as_float(r.y);
}
#else
__device__ __forceinline__ float xor16_sum(float v) { return v + __shfl_xor(v, 16, 64); }
#endif
#if __has_builtin(__builtin_amdgcn_permlane32_swap)
typedef unsigned u32x2b __attribute__((ext_vector_type(2)));
__device__ __forceinline__ float xor32_sum(float v) {
    u32x2b r = __builtin_amdgcn_permlane32_swap(__float_as_uint(v), __float_as_uint(v), false, false);
    return __uint_as_float(r.x) + __uint_as_float(r.y);
}
#else
__device__ __forceinline__ float xor32_sum(float v) { return v + __shfl_xor(v, 32, 64); }
#endif

// coalesced x-window staging for one pixel (h,w) of image base xb
__device__ __forceinline__ void stage_x(const float* __restrict__ xb,
                                        ushort* __restrict__ xw,
                                        int t, int h, int w) {
    const int w2 = 2 * w;
    #pragma unroll
    for (int pass = 0; pass < 9; ++pass) {
        int idx = pass * 1024 + t;
        int q4 = idx & 3, r = idx >> 2;
        int kh = r % 9, i = r / 9;
        float4 v = *(const float4*)(xb + (i * HI + 2 * h + kh) * WI + 4 * q4);
        const float* ve = &v.x;
        #pragma unroll
        for (int e = 0; e < 4; ++e) {
            int kw = 4 * q4 + e - w2;
            if ((unsigned)kw < 9u) xw[i * XP + kh * 9 + kw] = f2bf(ve[e]);
        }
    }
    if (w >= 4) {
        for (int r = t; r < CI * 9; r += 1024) {
            int kh = r % 9, i = r / 9;
            float4 v = *(const float4*)(xb + (i * HI + 2 * h + kh) * WI + 16);
            const float* ve = &v.x;
            #pragma unroll
            for (int e = 0; e < 4; ++e) {
                int kw = 16 + e - w2;
                if ((unsigned)kw < 9u) xw[i * XP + kh * 9 + kw] = f2bf(ve[e]);
            }
        }
    }
}

__global__ __launch_bounds__(1024) void caps_kernel(
    const float* __restrict__ x,     // [16,256,1,20,20]
    const float* __restrict__ Wt,    // [256,1,9,9]
    const float* __restrict__ bias,  // [32,8,1,1]
    float* __restrict__ out)         // [16,32,8,6,6]
{
    __shared__ __align__(16) ushort xw[CI * XP];        // 53248 B
    __shared__ __align__(16) ushort wl[CO * NO * XP];   // 53248 B
    __shared__ __align__(16) float  smx[4 * 256];       // softmax partials [wf][i]
    __shared__ __align__(16) float  pre[4 * 256];       // preact partials [wi][c*8+n]
    __shared__ __align__(16) float  act[256];           // activation broadcast

    const int t   = threadIdx.x, blk = blockIdx.x;
    const int b   = blk & 15;                 // same image for all this block's pixels
    const int npix = (blk < 64) ? 3 : 2;      // 64*3 + 192*2 = 576 pixels
    const float* xb = x + b * CI * HI * WI;

    const int wid = t >> 6, l = t & 63;
    const int q = l >> 4, il = l & 15;
    const int wf = wid >> 2, wi = wid & 3;

    // ---- one-time staging: W (k-major, pitch 104), pads, pixel-0 x
    for (int p = t; p < CO * NO * NTAP; p += 1024) {
        int f = p / NTAP, k = p - f * NTAP;
        wl[f * XP + k] = f2bf(Wt[p]);
    }
    {
        int i = t >> 2, s4 = t & 3;
        #pragma unroll
        for (int j = 0; j < 6; ++j) {
            int k = NTAP + s4 * 6 + j;
            if (k < XP) { xw[i * XP + k] = 0; wl[i * XP + k] = 0; }
        }
    }
    stage_x(xb, xw, t, (blk >> 4) / WO, (blk >> 4) % WO);

    const float bias_r = (t < 256) ? bias[t] : 0.f;

    for (int p = 0; p < npix; ++p) {
        const int hw = (blk + 256 * p) >> 4;     // 0..35, unique across blocks
        const int h  = hw / WO, w = hw % WO;

        __syncthreads();   // staged x visible (and prior routing's LDS reads done)

        // ---- conv via MFMA: votes^T
        f32x4 acc[4][4];
        #pragma unroll
        for (int tf = 0; tf < 4; ++tf)
            #pragma unroll
            for (int ti = 0; ti < 4; ++ti)
                acc[tf][ti] = (f32x4){0.f, 0.f, 0.f, 0.f};

        #pragma unroll
        for (int ks = 0; ks < 3; ++ks) {
            const int ko = ks * 32 + q * 8;
            bf16x8 af[4], bv[4];
            #pragma unroll
            for (int tf = 0; tf < 4; ++tf)
                af[tf] = *(const bf16x8*)&wl[(wf * 64 + tf * 16 + il) * XP + ko];
            #pragma unroll
            for (int ti = 0; ti < 4; ++ti)
                bv[ti] = *(const bf16x8*)&xw[(wi * 64 + ti * 16 + il) * XP + ko];
            #pragma unroll
            for (int tf = 0; tf < 4; ++tf)
                #pragma unroll
                for (int ti = 0; ti < 4; ++ti)
                    acc[tf][ti] = __builtin_amdgcn_mfma_f32_16x16x32_bf16(
                        af[tf], bv[ti], acc[tf][ti], 0, 0, 0);
        }

        __syncthreads();   // conv reads of xw complete -> xw free for restage

        // ---- stage next pixel's x now; its latency hides under routing
        if (p + 1 < npix) {
            const int hwn = (blk + 256 * (p + 1)) >> 4;
            stage_x(xb, xw, t, hwn / WO, hwn % WO);
        }

        // ---- dynamic routing, 3 iterations (R7-verified algebra)
        float lg[4][4];
        #pragma unroll
        for (int tf = 0; tf < 4; ++tf)
            #pragma unroll
            for (int ti = 0; ti < 4; ++ti) lg[tf][ti] = 0.f;

        #pragma unroll
        for (int it = 0; it < 3; ++it) {
            // --- preact partials pp[tf][r]
            float pp[4][4];
            if (it == 0) {
                #pragma unroll
                for (int tf = 0; tf < 4; ++tf)
                    #pragma unroll
                    for (int r = 0; r < 4; ++r)
                        pp[tf][r] = (acc[tf][0][r] + acc[tf][1][r]
                                   + acc[tf][2][r] + acc[tf][3][r]) * 0.03125f;
            } else {
                float e[4][4], srow[4] = {0.f, 0.f, 0.f, 0.f};
                #pragma unroll
                for (int tf = 0; tf < 4; ++tf)
                    #pragma unroll
                    for (int ti = 0; ti < 4; ++ti) {
                        e[tf][ti] = __expf(lg[tf][ti]);
                        srow[ti] += e[tf][ti];
                    }
                #pragma unroll
                for (int ti = 0; ti < 4; ++ti)
                    srow[ti] = xor32_sum(srow[ti]);   // other c-half, VALU
                if (q == 0) {
                    #pragma unroll
                    for (int ti = 0; ti < 4; ++ti)
                        smx[wf * 256 + wi * 64 + ti * 16 + il] = srow[ti];
                }
                __syncthreads();
                float rtot[4];
                #pragma unroll
                for (int ti = 0; ti < 4; ++ti) {
                    int i = wi * 64 + ti * 16 + il;
                    rtot[ti] = __builtin_amdgcn_rcpf(
                        smx[i] + smx[256 + i] + smx[512 + i] + smx[768 + i]);
                }
                float route[4][4];
                #pragma unroll
                for (int tf = 0; tf < 4; ++tf)
                    #pragma unroll
                    for (int ti = 0; ti < 4; ++ti) route[tf][ti] = e[tf][ti] * rtot[ti];
                #pragma unroll
                for (int tf = 0; tf < 4; ++tf)
                    #pragma unroll
                    for (int r = 0; r < 4; ++r)
                        pp[tf][r] = route[tf][0] * acc[tf][0][r] + route[tf][1] * acc[tf][1][r]
                                  + route[tf][2] * acc[tf][2][r] + route[tf][3] * acc[tf][3][r];
            }

            // --- reduce over il (16 i-lanes) on the VALU pipe (DPP)
            #pragma unroll
            for (int tf = 0; tf < 4; ++tf)
                #pragma unroll
                for (int r = 0; r < 4; ++r)
                    pp[tf][r] = row16_sum_tail(pp[tf][r]);
            if (il == 15) {
                #pragma unroll
                for (int tf = 0; tf < 4; ++tf) {
                    int c = wf * 8 + tf * 2 + (q >> 1);
                    f32x4 vv = {pp[tf][0], pp[tf][1], pp[tf][2], pp[tf][3]};
                    *(f32x4*)&pre[wi * 256 + c * 8 + (q & 1) * 4] = vv;
                }
            }
            __syncthreads();

            // --- finish preact + squash (threads 0..255), broadcast act
            if (t < 256) {
                float s = bias_r + pre[t] + pre[256 + t] + pre[512 + t] + pre[768 + t];
                float sq = grp8_sum_all(s * s);       // sum over 8 n-lanes (DPP)
                float a = s * __builtin_amdgcn_sqrtf(sq) * __builtin_amdgcn_rcpf(1.f + sq);
                if (it == 2) {
                    int c = t >> 3, n = t & 7;
                    out[(((b * CO + c) * NO + n) * HO + h) * WO + w] = a;
                } else {
                    act[t] = a;
                }
            }

            // --- distances -> logits (skip on last iter)
            if (it < 2) {
                __syncthreads();   // act ready
                #pragma unroll
                for (int tf = 0; tf < 4; ++tf) {
                    int c = wf * 8 + tf * 2 + (q >> 1);
                    f32x4 av = *(const f32x4*)&act[c * 8 + (q & 1) * 4];
                    #pragma unroll
                    for (int ti = 0; ti < 4; ++ti) {
                        float d = acc[tf][ti][0] * av[0] + acc[tf][ti][1] * av[1]
                                + acc[tf][ti][2] * av[2] + acc[tf][ti][3] * av[3];
                        lg[tf][ti] += xor16_sum(d);   // other n-half, VALU
                    }
                }
            }
        }
    }
}

extern "C" void kernel_launch(void* const* d_in, const int* in_sizes, int n_in,
                              void* d_out, int out_size, void* d_ws, size_t ws_size,
                              hipStream_t stream) {
    const float* x    = (const float*)d_in[0];
    const float* Wt   = (const float*)d_in[1];
    const float* bias = (const float*)d_in[2];
    float* out = (float*)d_out;
    caps_kernel<<<NBLK, 1024, 0, stream>>>(x, Wt, bias, out);
}